// Round 9
// baseline (142.907 us; speedup 1.0000x reference)
//
#include <hip/hip_runtime.h>
#include <math.h>

#define NF 1000
#define NC 1000
#define NB 16384
#define NV 250          // NF/4 float4s per row (exact: 1000 = 4*250)
#define ALPHA_C 0.5f
#define BETA_C 0.003f
#define GAMMA_C 0.001f
#define MAXL 512        // LDS row-list capacity (class count ~16.4 +- 4; huge margin)
#define NCHUNK 16       // class chunks for column partial sums
#define NFB 4           // feature-block count (4 x 256 >= 1000)

__device__ __forceinline__ float wave_sum(float v) {
#pragma unroll
    for (int off = 32; off > 0; off >>= 1) v += __shfl_xor(v, off, 64);
    return v;
}
__device__ __forceinline__ float wave_max(float v) {
#pragma unroll
    for (int off = 32; off > 0; off >>= 1) v = fmaxf(v, __shfl_xor(v, off, 64));
    return v;
}

// One block per class. Row list built by scanning y. Main loop: one WAVE per
// row, no block barriers, 2-deep software pipeline, all state in named
// float4 registers (no local arrays -> no scratch spill).
__global__ __launch_bounds__(256) void class_fused(
    const float* __restrict__ x, const int* __restrict__ y,
    const float* __restrict__ centers,
    float* __restrict__ new_centers, float4* __restrict__ partials,
    int* __restrict__ done_cnt) {
    __shared__ int list[MAXL];
    __shared__ int lcount;
    __shared__ float4 smx[NV];
    __shared__ float sb[8];
    const int c = blockIdx.x, t = threadIdx.x;
    const int wid = t >> 6, lane = t & 63;
    if (c == 0 && t == 0) *done_cnt = 0;   // zero the fused-tail counter (stream order)
    if (t == 0) lcount = 0;
    __syncthreads();

    const int4* y4 = (const int4*)y;
    for (int i = t; i < NB / 4; i += 256) {
        int4 v = y4[i];
        int b = 4 * i;
        if (v.x == c) { int p = atomicAdd(&lcount, 1); list[p & (MAXL - 1)] = b; }
        if (v.y == c) { int p = atomicAdd(&lcount, 1); list[p & (MAXL - 1)] = b + 1; }
        if (v.z == c) { int p = atomicAdd(&lcount, 1); list[p & (MAXL - 1)] = b + 2; }
        if (v.w == c) { int p = atomicAdd(&lcount, 1); list[p & (MAXL - 1)] = b + 3; }
    }
    __syncthreads();
    const int n = lcount;

    // class center row, lane-sliced (same copy in every wave)
    const float4* crow = (const float4*)(centers + (size_t)c * NF);
    const bool tail = (lane < NV - 192);   // lane < 58
    const float4 z4 = make_float4(0.f, 0.f, 0.f, 0.f);
    const float4 c0 = crow[lane];
    const float4 c1 = crow[lane + 64];
    const float4 c2 = crow[lane + 128];
    const float4 c3 = tail ? crow[lane + 192] : z4;

    const int f4 = c >> 2;
    const int j_src = f4 >> 6, lane_src = f4 & 63, comp = c & 3;

    float4 a0 = z4, a1 = z4, a2 = z4, a3 = z4;
    float ce_acc = 0.f, s2_acc = 0.f;

    const float NEG = -INFINITY;
    const float4 ninf4 = make_float4(NEG, NEG, NEG, NEG);

    // preload first row for this wave
    float4 v0 = ninf4, v1 = ninf4, v2 = ninf4, v3 = ninf4;
    if (wid < n) {
        const float4* r = (const float4*)(x + (size_t)list[wid] * NF);
        v0 = r[lane]; v1 = r[lane + 64]; v2 = r[lane + 128];
        v3 = tail ? r[lane + 192] : ninf4;
    }

    for (int i = wid; i < n; i += 4) {
        // prefetch next row (independent of current processing)
        const int inx = i + 4;
        float4 n0 = ninf4, n1 = ninf4, n2 = ninf4, n3 = ninf4;
        if (inx < n) {
            const float4* r = (const float4*)(x + (size_t)list[inx] * NF);
            n0 = r[lane]; n1 = r[lane + 64]; n2 = r[lane + 128];
            n3 = tail ? r[lane + 192] : ninf4;
        }

        // ---- process current row (wave-local, no barriers) ----
        float m = fmaxf(fmaxf(v0.x, v0.y), fmaxf(v0.z, v0.w));
        m = fmaxf(m, fmaxf(fmaxf(v1.x, v1.y), fmaxf(v1.z, v1.w)));
        m = fmaxf(m, fmaxf(fmaxf(v2.x, v2.y), fmaxf(v2.z, v2.w)));
        m = fmaxf(m, fmaxf(fmaxf(v3.x, v3.y), fmaxf(v3.z, v3.w)));
        const float rmax = wave_max(m);

        float e = expf(v0.x - rmax) + expf(v0.y - rmax) +
                  expf(v0.z - rmax) + expf(v0.w - rmax);
        e += expf(v1.x - rmax) + expf(v1.y - rmax) +
             expf(v1.z - rmax) + expf(v1.w - rmax);
        e += expf(v2.x - rmax) + expf(v2.y - rmax) +
             expf(v2.z - rmax) + expf(v2.w - rmax);
        e += expf(v3.x - rmax) + expf(v3.y - rmax) +
             expf(v3.z - rmax) + expf(v3.w - rmax);   // -INF slots -> 0

        float d;
        {
            float dx = v0.x - c0.x, dy = v0.y - c0.y, dz = v0.z - c0.z, dw = v0.w - c0.w;
            d = dx * dx + dy * dy + dz * dz + dw * dw;
            a0.x += v0.x; a0.y += v0.y; a0.z += v0.z; a0.w += v0.w;
        }
        {
            float dx = v1.x - c1.x, dy = v1.y - c1.y, dz = v1.z - c1.z, dw = v1.w - c1.w;
            d += dx * dx + dy * dy + dz * dz + dw * dw;
            a1.x += v1.x; a1.y += v1.y; a1.z += v1.z; a1.w += v1.w;
        }
        {
            float dx = v2.x - c2.x, dy = v2.y - c2.y, dz = v2.z - c2.z, dw = v2.w - c2.w;
            d += dx * dx + dy * dy + dz * dz + dw * dw;
            a2.x += v2.x; a2.y += v2.y; a2.z += v2.z; a2.w += v2.w;
        }
        if (tail) {
            float dx = v3.x - c3.x, dy = v3.y - c3.y, dz = v3.z - c3.z, dw = v3.w - c3.w;
            d += dx * dx + dy * dy + dz * dz + dw * dw;
            a3.x += v3.x; a3.y += v3.y; a3.z += v3.z; a3.w += v3.w;
        }
        const float se = wave_sum(e);
        const float sd = wave_sum(d);

        // x[b][c]: block-uniform source slot, single shuffle broadcast
        float4 xj = (j_src == 0) ? v0 : (j_src == 1) ? v1 : (j_src == 2) ? v2 : v3;
        float cand = (comp == 0) ? xj.x : (comp == 1) ? xj.y : (comp == 2) ? xj.z : xj.w;
        const float xy = __shfl(cand, lane_src, 64);

        ce_acc += -(xy - rmax - logf(se));
        s2_acc += sd;

        v0 = n0; v1 = n1; v2 = n2; v3 = n3;
    }

    // deterministic staged merge of per-wave partial sums into smx
    for (int w = 0; w < 4; w++) {
        if (wid == w) {
            if (w == 0) {
                smx[lane] = a0; smx[lane + 64] = a1; smx[lane + 128] = a2;
                if (tail) smx[lane + 192] = a3;
            } else {
                float4 s;
                s = smx[lane];      s.x += a0.x; s.y += a0.y; s.z += a0.z; s.w += a0.w; smx[lane] = s;
                s = smx[lane + 64]; s.x += a1.x; s.y += a1.y; s.z += a1.z; s.w += a1.w; smx[lane + 64] = s;
                s = smx[lane + 128]; s.x += a2.x; s.y += a2.y; s.z += a2.z; s.w += a2.w; smx[lane + 128] = s;
                if (tail) { s = smx[lane + 192]; s.x += a3.x; s.y += a3.y; s.z += a3.z; s.w += a3.w; smx[lane + 192] = s; }
            }
        }
        __syncthreads();
    }
    if (lane == 0) { sb[wid] = ce_acc; sb[4 + wid] = s2_acc; }
    __syncthreads();

    // epilogue on wave 0 only
    if (wid == 0) {
        const float inv = (n > 0) ? 1.f / (float)n : 0.f;
        const float has = (n > 0) ? 1.f : 0.f;
        float lsq = 0.f, lmd2 = 0.f;
        float4* ncrow = (float4*)(new_centers + (size_t)c * NF);
#pragma unroll
        for (int j = 0; j < 4; j++) {
            const int idx = lane + 64 * j;
            if (idx < NV) {
                const float4 s = smx[idx];
                const float4 cv = (j == 0) ? c0 : (j == 1) ? c1 : (j == 2) ? c2 : c3;
                float4 md, nc;
                md.x = has * (s.x * inv - cv.x);
                md.y = has * (s.y * inv - cv.y);
                md.z = has * (s.z * inv - cv.z);
                md.w = has * (s.w * inv - cv.w);
                nc.x = cv.x + ALPHA_C * md.x; nc.y = cv.y + ALPHA_C * md.y;
                nc.z = cv.z + ALPHA_C * md.z; nc.w = cv.w + ALPHA_C * md.w;
                ncrow[idx] = nc;
                lsq  += nc.x * nc.x + nc.y * nc.y + nc.z * nc.z + nc.w * nc.w;
                lmd2 += md.x * md.x + md.y * md.y + md.z * md.z + md.w * md.w;
            }
        }
        const float sq = wave_sum(lsq);
        const float md2 = wave_sum(lmd2);
        if (lane == 0) {
            const float ces = sb[0] + sb[1] + sb[2] + sb[3];
            const float s2 = sb[4] + sb[5] + sb[6] + sb[7];
            // per-class intra mean: S2/n - alpha*(2-alpha)*||md||^2
            const float intra = (n > 0) ? (s2 * inv - ALPHA_C * (2.f - ALPHA_C) * md2) : 0.f;
            partials[c] = make_float4(ces, s2, sq, intra);
        }
    }
}

// Fused column-partial + finalize (last-block-done pattern).
// Grid (NFB, NCHUNK) = 64 blocks; each writes its s_part chunk; the last
// block to finish reduces s_part + partials and writes the scalar output.
__global__ __launch_bounds__(256) void col_finalize(
    const float* __restrict__ new_centers, const float4* __restrict__ partials,
    float* __restrict__ s_part, int* __restrict__ done_cnt,
    float* __restrict__ out) {
    const int t = threadIdx.x;
    const int f = blockIdx.x * 256 + t;
    if (f < NF) {
        float acc = 0.f;
        for (int c = blockIdx.y; c < NC; c += NCHUNK)
            acc += new_centers[(size_t)c * NF + f];
        s_part[blockIdx.y * NF + f] = acc;
    }
    __threadfence();                       // make s_part visible device-wide
    __shared__ int s_last;
    __syncthreads();                       // all writes in block issued
    if (t == 0) s_last = atomicAdd(done_cnt, 1);
    __syncthreads();
    if (s_last != NFB * NCHUNK - 1) return;

    // ---- last block: final reduction (s_part + partials are L2-hot) ----
    __shared__ float sb[80];
    float ssq = 0.f, ces = 0.f, s2 = 0.f, sq = 0.f, intra = 0.f;
    for (int col = t; col < NC; col += 256) {
        float s = 0.f;
#pragma unroll
        for (int k = 0; k < NCHUNK; k++) s += s_part[k * NF + col];
        ssq += s * s;
        float4 p = partials[col];
        ces += p.x; s2 += p.y; sq += p.z; intra += p.w;
    }
    float w0 = wave_sum(ssq), w1 = wave_sum(ces), w2 = wave_sum(s2);
    float w3 = wave_sum(sq), w4 = wave_sum(intra);
    const int wid = t >> 6, lane = t & 63;
    if (lane == 0) {
        sb[wid] = w0; sb[16 + wid] = w1; sb[32 + wid] = w2;
        sb[48 + wid] = w3; sb[64 + wid] = w4;
    }
    __syncthreads();
    if (t == 0) {
        float Sssq = 0.f, Sces = 0.f, Ss2 = 0.f, Ssq = 0.f, Sintra = 0.f;
        for (int k = 0; k < 4; k++) {
            Sssq += sb[k]; Sces += sb[16 + k]; Ss2 += sb[32 + k];
            Ssq += sb[48 + k]; Sintra += sb[64 + k];
        }
        float cem = Sces / (float)NB;
        float cl = Ss2 / (float)NB;
        float num_pairs = (float)NC * (float)(NC - 1) * 0.5f;
        float inter = ((float)NC * Ssq - Sssq) / num_pairs;
        float intra_l = Sintra / (float)NC;
        out[0] = cem + BETA_C * cl + GAMMA_C * inter + GAMMA_C * intra_l;
    }
}

extern "C" void kernel_launch(void* const* d_in, const int* in_sizes, int n_in,
                              void* d_out, int out_size, void* d_ws, size_t ws_size,
                              hipStream_t stream) {
    const float* x = (const float*)d_in[0];
    const int* y = (const int*)d_in[1];
    const float* centers = (const float*)d_in[2];
    float* out = (float*)d_out;

    char* ws = (char*)d_ws;
    float* s_part      = (float*)(ws);                 // 16*1000*4 = 64,000 B
    float4* partials   = (float4*)(ws + 64000);        // 16,000 B
    int* done_cnt      = (int*)(ws + 80000);           // 64 B (padded)
    float* new_centers = (float*)(ws + 80064);         // 4,000,000 B
    // done_cnt is zeroed by class_fused block 0 (stream order); everything
    // else read is written this launch -- no memset needed

    class_fused<<<NC, 256, 0, stream>>>(x, y, centers, new_centers, partials,
                                        done_cnt);
    dim3 cgrid(NFB, NCHUNK);
    col_finalize<<<cgrid, 256, 0, stream>>>(new_centers, partials, s_part,
                                            done_cnt, out);
}

// Round 10
// 142.180 us; speedup vs baseline: 1.0051x; 1.0051x over previous
//
#include <hip/hip_runtime.h>
#include <math.h>

#define NF 1000
#define NC 1000
#define NB 16384
#define NV 250          // NF/4 float4s per row (exact: 1000 = 4*250)
#define ALPHA_C 0.5f
#define BETA_C 0.003f
#define GAMMA_C 0.001f
#define MAXL 512        // LDS row-list capacity (class count ~16.4 +- 4; huge margin)
#define NCHUNK 16       // class chunks for column partial sums
#define NFB 4           // feature-block count (4 x 256 >= 1000)
#define WAVES 8         // waves per class block (512 threads)

__device__ __forceinline__ float wave_sum(float v) {
#pragma unroll
    for (int off = 32; off > 0; off >>= 1) v += __shfl_xor(v, off, 64);
    return v;
}
__device__ __forceinline__ float wave_max(float v) {
#pragma unroll
    for (int off = 32; off > 0; off >>= 1) v = fmaxf(v, __shfl_xor(v, off, 64));
    return v;
}

// One block (512 threads = 8 waves) per class. Row list built by scanning y
// (8 int4/thread). Main loop: one WAVE per row, no block barriers, 2-deep
// software pipeline, all state in named float4 registers (no scratch).
// Single-barrier parallel LDS merge; thread-per-f4 epilogue.
__global__ __launch_bounds__(512) void class_fused(
    const float* __restrict__ x, const int* __restrict__ y,
    const float* __restrict__ centers,
    float* __restrict__ new_centers, float4* __restrict__ partials,
    int* __restrict__ done_cnt) {
    __shared__ int list[MAXL];
    __shared__ int lcount;
    __shared__ float4 smx8[WAVES][NV];     // 32 KB per-wave partial sums
    __shared__ float sb_ce[WAVES], sb_s2[WAVES], sb_lsq[WAVES], sb_md2[WAVES];
    const int c = blockIdx.x, t = threadIdx.x;
    const int wid = t >> 6, lane = t & 63;
    if (c == 0 && t == 0) *done_cnt = 0;   // zero fused-tail counter (stream order)
    if (t == 0) lcount = 0;
    __syncthreads();

    const int4* y4 = (const int4*)y;
#pragma unroll
    for (int i = t; i < NB / 4; i += 512) {
        int4 v = y4[i];
        int b = 4 * i;
        if (v.x == c) { int p = atomicAdd(&lcount, 1); list[p & (MAXL - 1)] = b; }
        if (v.y == c) { int p = atomicAdd(&lcount, 1); list[p & (MAXL - 1)] = b + 1; }
        if (v.z == c) { int p = atomicAdd(&lcount, 1); list[p & (MAXL - 1)] = b + 2; }
        if (v.w == c) { int p = atomicAdd(&lcount, 1); list[p & (MAXL - 1)] = b + 3; }
    }
    __syncthreads();
    const int n = lcount;

    // class center row, lane-sliced (same copy in every wave)
    const float4* crow = (const float4*)(centers + (size_t)c * NF);
    const bool tail = (lane < NV - 192);   // lane < 58
    const float4 z4 = make_float4(0.f, 0.f, 0.f, 0.f);
    const float4 c0 = crow[lane];
    const float4 c1 = crow[lane + 64];
    const float4 c2 = crow[lane + 128];
    const float4 c3 = tail ? crow[lane + 192] : z4;

    const int f4 = c >> 2;
    const int j_src = f4 >> 6, lane_src = f4 & 63, comp = c & 3;

    float4 a0 = z4, a1 = z4, a2 = z4, a3 = z4;
    float ce_acc = 0.f, s2_acc = 0.f;

    const float NEG = -INFINITY;
    const float4 ninf4 = make_float4(NEG, NEG, NEG, NEG);

    // preload first row for this wave
    float4 v0 = ninf4, v1 = ninf4, v2 = ninf4, v3 = ninf4;
    if (wid < n) {
        const float4* r = (const float4*)(x + (size_t)list[wid] * NF);
        v0 = r[lane]; v1 = r[lane + 64]; v2 = r[lane + 128];
        v3 = tail ? r[lane + 192] : ninf4;
    }

    for (int i = wid; i < n; i += WAVES) {
        // prefetch next row (independent of current processing)
        const int inx = i + WAVES;
        float4 n0 = ninf4, n1 = ninf4, n2 = ninf4, n3 = ninf4;
        if (inx < n) {
            const float4* r = (const float4*)(x + (size_t)list[inx] * NF);
            n0 = r[lane]; n1 = r[lane + 64]; n2 = r[lane + 128];
            n3 = tail ? r[lane + 192] : ninf4;
        }

        // ---- process current row (wave-local, no barriers) ----
        float m = fmaxf(fmaxf(v0.x, v0.y), fmaxf(v0.z, v0.w));
        m = fmaxf(m, fmaxf(fmaxf(v1.x, v1.y), fmaxf(v1.z, v1.w)));
        m = fmaxf(m, fmaxf(fmaxf(v2.x, v2.y), fmaxf(v2.z, v2.w)));
        m = fmaxf(m, fmaxf(fmaxf(v3.x, v3.y), fmaxf(v3.z, v3.w)));
        const float rmax = wave_max(m);

        float e = __expf(v0.x - rmax) + __expf(v0.y - rmax) +
                  __expf(v0.z - rmax) + __expf(v0.w - rmax);
        e += __expf(v1.x - rmax) + __expf(v1.y - rmax) +
             __expf(v1.z - rmax) + __expf(v1.w - rmax);
        e += __expf(v2.x - rmax) + __expf(v2.y - rmax) +
             __expf(v2.z - rmax) + __expf(v2.w - rmax);
        e += __expf(v3.x - rmax) + __expf(v3.y - rmax) +
             __expf(v3.z - rmax) + __expf(v3.w - rmax);   // -INF slots -> 0

        float d;
        {
            float dx = v0.x - c0.x, dy = v0.y - c0.y, dz = v0.z - c0.z, dw = v0.w - c0.w;
            d = dx * dx + dy * dy + dz * dz + dw * dw;
            a0.x += v0.x; a0.y += v0.y; a0.z += v0.z; a0.w += v0.w;
        }
        {
            float dx = v1.x - c1.x, dy = v1.y - c1.y, dz = v1.z - c1.z, dw = v1.w - c1.w;
            d += dx * dx + dy * dy + dz * dz + dw * dw;
            a1.x += v1.x; a1.y += v1.y; a1.z += v1.z; a1.w += v1.w;
        }
        {
            float dx = v2.x - c2.x, dy = v2.y - c2.y, dz = v2.z - c2.z, dw = v2.w - c2.w;
            d += dx * dx + dy * dy + dz * dz + dw * dw;
            a2.x += v2.x; a2.y += v2.y; a2.z += v2.z; a2.w += v2.w;
        }
        if (tail) {
            float dx = v3.x - c3.x, dy = v3.y - c3.y, dz = v3.z - c3.z, dw = v3.w - c3.w;
            d += dx * dx + dy * dy + dz * dz + dw * dw;
            a3.x += v3.x; a3.y += v3.y; a3.z += v3.z; a3.w += v3.w;
        }
        const float se = wave_sum(e);
        const float sd = wave_sum(d);

        // x[b][c]: block-uniform source slot, single shuffle broadcast
        float4 xj = (j_src == 0) ? v0 : (j_src == 1) ? v1 : (j_src == 2) ? v2 : v3;
        float cand = (comp == 0) ? xj.x : (comp == 1) ? xj.y : (comp == 2) ? xj.z : xj.w;
        const float xy = __shfl(cand, lane_src, 64);

        ce_acc += -(xy - rmax - __logf(se));
        s2_acc += sd;

        v0 = n0; v1 = n1; v2 = n2; v3 = n3;
    }

    // parallel merge: each wave writes its own LDS slice; ONE barrier
    smx8[wid][lane] = a0;
    smx8[wid][lane + 64] = a1;
    smx8[wid][lane + 128] = a2;
    if (tail) smx8[wid][lane + 192] = a3;
    if (lane == 0) { sb_ce[wid] = ce_acc; sb_s2[wid] = s2_acc; }
    __syncthreads();

    // epilogue: thread-per-f4 (t < 250)
    float lsq = 0.f, lmd2 = 0.f;
    const float inv = (n > 0) ? 1.f / (float)n : 0.f;
    const float has = (n > 0) ? 1.f : 0.f;
    if (t < NV) {
        float4 s = smx8[0][t];
#pragma unroll
        for (int w = 1; w < WAVES; w++) {
            float4 p = smx8[w][t];
            s.x += p.x; s.y += p.y; s.z += p.z; s.w += p.w;
        }
        const float4 cv = crow[t];          // L2-hot reload, coalesced
        float4 md, nc;
        md.x = has * (s.x * inv - cv.x);
        md.y = has * (s.y * inv - cv.y);
        md.z = has * (s.z * inv - cv.z);
        md.w = has * (s.w * inv - cv.w);
        nc.x = cv.x + ALPHA_C * md.x; nc.y = cv.y + ALPHA_C * md.y;
        nc.z = cv.z + ALPHA_C * md.z; nc.w = cv.w + ALPHA_C * md.w;
        ((float4*)(new_centers + (size_t)c * NF))[t] = nc;
        lsq  = nc.x * nc.x + nc.y * nc.y + nc.z * nc.z + nc.w * nc.w;
        lmd2 = md.x * md.x + md.y * md.y + md.z * md.z + md.w * md.w;
    }
    lsq = wave_sum(lsq);
    lmd2 = wave_sum(lmd2);
    if (lane == 0) { sb_lsq[wid] = lsq; sb_md2[wid] = lmd2; }
    __syncthreads();
    if (t == 0) {
        float sq = 0.f, md2 = 0.f, ces = 0.f, s2 = 0.f;
#pragma unroll
        for (int w = 0; w < WAVES; w++) {
            sq += sb_lsq[w]; md2 += sb_md2[w];
            ces += sb_ce[w]; s2 += sb_s2[w];
        }
        // per-class intra mean: S2/n - alpha*(2-alpha)*||md||^2
        const float intra = (n > 0) ? (s2 * inv - ALPHA_C * (2.f - ALPHA_C) * md2) : 0.f;
        partials[c] = make_float4(ces, s2, sq, intra);
    }
}

// Fused column-partial + finalize (last-block-done pattern).
// Grid (NFB, NCHUNK) = 64 blocks; each writes its s_part chunk; the last
// block to finish reduces s_part + partials and writes the scalar output.
__global__ __launch_bounds__(256) void col_finalize(
    const float* __restrict__ new_centers, const float4* __restrict__ partials,
    float* __restrict__ s_part, int* __restrict__ done_cnt,
    float* __restrict__ out) {
    const int t = threadIdx.x;
    const int f = blockIdx.x * 256 + t;
    if (f < NF) {
        float acc = 0.f;
        for (int c = blockIdx.y; c < NC; c += NCHUNK)
            acc += new_centers[(size_t)c * NF + f];
        s_part[blockIdx.y * NF + f] = acc;
    }
    __threadfence();                       // make s_part visible device-wide
    __shared__ int s_last;
    __syncthreads();                       // all writes in block issued
    if (t == 0) s_last = atomicAdd(done_cnt, 1);
    __syncthreads();
    if (s_last != NFB * NCHUNK - 1) return;

    // ---- last block: final reduction (s_part + partials are L2-hot) ----
    __shared__ float sb[80];
    float ssq = 0.f, ces = 0.f, s2 = 0.f, sq = 0.f, intra = 0.f;
    for (int col = t; col < NC; col += 256) {
        float s = 0.f;
#pragma unroll
        for (int k = 0; k < NCHUNK; k++) s += s_part[k * NF + col];
        ssq += s * s;
        float4 p = partials[col];
        ces += p.x; s2 += p.y; sq += p.z; intra += p.w;
    }
    float w0 = wave_sum(ssq), w1 = wave_sum(ces), w2 = wave_sum(s2);
    float w3 = wave_sum(sq), w4 = wave_sum(intra);
    const int wid = t >> 6, lane = t & 63;
    if (lane == 0) {
        sb[wid] = w0; sb[16 + wid] = w1; sb[32 + wid] = w2;
        sb[48 + wid] = w3; sb[64 + wid] = w4;
    }
    __syncthreads();
    if (t == 0) {
        float Sssq = 0.f, Sces = 0.f, Ss2 = 0.f, Ssq = 0.f, Sintra = 0.f;
        for (int k = 0; k < 4; k++) {
            Sssq += sb[k]; Sces += sb[16 + k]; Ss2 += sb[32 + k];
            Ssq += sb[48 + k]; Sintra += sb[64 + k];
        }
        float cem = Sces / (float)NB;
        float cl = Ss2 / (float)NB;
        float num_pairs = (float)NC * (float)(NC - 1) * 0.5f;
        float inter = ((float)NC * Ssq - Sssq) / num_pairs;
        float intra_l = Sintra / (float)NC;
        out[0] = cem + BETA_C * cl + GAMMA_C * inter + GAMMA_C * intra_l;
    }
}

extern "C" void kernel_launch(void* const* d_in, const int* in_sizes, int n_in,
                              void* d_out, int out_size, void* d_ws, size_t ws_size,
                              hipStream_t stream) {
    const float* x = (const float*)d_in[0];
    const int* y = (const int*)d_in[1];
    const float* centers = (const float*)d_in[2];
    float* out = (float*)d_out;

    char* ws = (char*)d_ws;
    float* s_part      = (float*)(ws);                 // 16*1000*4 = 64,000 B
    float4* partials   = (float4*)(ws + 64000);        // 16,000 B
    int* done_cnt      = (int*)(ws + 80000);           // 64 B (padded)
    float* new_centers = (float*)(ws + 80064);         // 4,000,000 B
    // done_cnt is zeroed by class_fused block 0 (stream order); everything
    // else read is written this launch -- no memset needed

    class_fused<<<NC, 512, 0, stream>>>(x, y, centers, new_centers, partials,
                                        done_cnt);
    dim3 cgrid(NFB, NCHUNK);
    col_finalize<<<cgrid, 256, 0, stream>>>(new_centers, partials, s_part,
                                            done_cnt, out);
}

// Round 11
// 134.987 us; speedup vs baseline: 1.0587x; 1.0533x over previous
//
#include <hip/hip_runtime.h>
#include <math.h>

#define NF 1000
#define NC 1000
#define NB 16384
#define NV 250          // NF/4 float4s per row (exact: 1000 = 4*250)
#define ALPHA_C 0.5f
#define BETA_C 0.003f
#define GAMMA_C 0.001f
#define MAXL 512        // LDS row-list capacity (class count ~16.4 +- 4; huge margin)

__device__ __forceinline__ float wave_sum(float v) {
#pragma unroll
    for (int off = 32; off > 0; off >>= 1) v += __shfl_xor(v, off, 64);
    return v;
}
__device__ __forceinline__ float wave_max(float v) {
#pragma unroll
    for (int off = 32; off > 0; off >>= 1) v = fmaxf(v, __shfl_xor(v, off, 64));
    return v;
}

// One block per class. Row list built by scanning y. Main loop: one WAVE per
// row, no block barriers, 2-deep software pipeline, all state in named
// float4 registers. __launch_bounds__(256,4): VGPR cap 128 (>= ~100 needed)
// so the pipeline state fits with NO scratch spill (the default heuristic
// capped at 52 VGPR and spilled -- R7/R10 WRITE_SIZE explosions).
__global__ __launch_bounds__(256, 4) void class_fused(
    const float* __restrict__ x, const int* __restrict__ y,
    const float* __restrict__ centers,
    float* __restrict__ new_centers, float4* __restrict__ partials) {
    __shared__ int list[MAXL];
    __shared__ int lcount;
    __shared__ float4 smx[NV];
    __shared__ float sb[8];
    const int c = blockIdx.x, t = threadIdx.x;
    const int wid = t >> 6, lane = t & 63;
    if (t == 0) lcount = 0;
    __syncthreads();

    const int4* y4 = (const int4*)y;
    for (int i = t; i < NB / 4; i += 256) {
        int4 v = y4[i];
        int b = 4 * i;
        if (v.x == c) { int p = atomicAdd(&lcount, 1); list[p & (MAXL - 1)] = b; }
        if (v.y == c) { int p = atomicAdd(&lcount, 1); list[p & (MAXL - 1)] = b + 1; }
        if (v.z == c) { int p = atomicAdd(&lcount, 1); list[p & (MAXL - 1)] = b + 2; }
        if (v.w == c) { int p = atomicAdd(&lcount, 1); list[p & (MAXL - 1)] = b + 3; }
    }
    __syncthreads();
    const int n = lcount;

    // class center row, lane-sliced (same copy in every wave)
    const float4* crow = (const float4*)(centers + (size_t)c * NF);
    const bool tail = (lane < NV - 192);   // lane < 58
    const float4 z4 = make_float4(0.f, 0.f, 0.f, 0.f);
    const float4 c0 = crow[lane];
    const float4 c1 = crow[lane + 64];
    const float4 c2 = crow[lane + 128];
    const float4 c3 = tail ? crow[lane + 192] : z4;

    const int f4 = c >> 2;
    const int j_src = f4 >> 6, lane_src = f4 & 63, comp = c & 3;

    float4 a0 = z4, a1 = z4, a2 = z4, a3 = z4;
    float ce_acc = 0.f, s2_acc = 0.f;

    const float NEG = -INFINITY;
    const float4 ninf4 = make_float4(NEG, NEG, NEG, NEG);

    // preload first row for this wave
    float4 v0 = ninf4, v1 = ninf4, v2 = ninf4, v3 = ninf4;
    if (wid < n) {
        const float4* r = (const float4*)(x + (size_t)list[wid] * NF);
        v0 = r[lane]; v1 = r[lane + 64]; v2 = r[lane + 128];
        v3 = tail ? r[lane + 192] : ninf4;
    }

    for (int i = wid; i < n; i += 4) {
        // prefetch next row (independent of current processing)
        const int inx = i + 4;
        float4 n0 = ninf4, n1 = ninf4, n2 = ninf4, n3 = ninf4;
        if (inx < n) {
            const float4* r = (const float4*)(x + (size_t)list[inx] * NF);
            n0 = r[lane]; n1 = r[lane + 64]; n2 = r[lane + 128];
            n3 = tail ? r[lane + 192] : ninf4;
        }

        // ---- process current row (wave-local, no barriers) ----
        float m = fmaxf(fmaxf(v0.x, v0.y), fmaxf(v0.z, v0.w));
        m = fmaxf(m, fmaxf(fmaxf(v1.x, v1.y), fmaxf(v1.z, v1.w)));
        m = fmaxf(m, fmaxf(fmaxf(v2.x, v2.y), fmaxf(v2.z, v2.w)));
        m = fmaxf(m, fmaxf(fmaxf(v3.x, v3.y), fmaxf(v3.z, v3.w)));
        const float rmax = wave_max(m);

        float e = __expf(v0.x - rmax) + __expf(v0.y - rmax) +
                  __expf(v0.z - rmax) + __expf(v0.w - rmax);
        e += __expf(v1.x - rmax) + __expf(v1.y - rmax) +
             __expf(v1.z - rmax) + __expf(v1.w - rmax);
        e += __expf(v2.x - rmax) + __expf(v2.y - rmax) +
             __expf(v2.z - rmax) + __expf(v2.w - rmax);
        e += __expf(v3.x - rmax) + __expf(v3.y - rmax) +
             __expf(v3.z - rmax) + __expf(v3.w - rmax);   // -INF slots -> 0

        float d;
        {
            float dx = v0.x - c0.x, dy = v0.y - c0.y, dz = v0.z - c0.z, dw = v0.w - c0.w;
            d = dx * dx + dy * dy + dz * dz + dw * dw;
            a0.x += v0.x; a0.y += v0.y; a0.z += v0.z; a0.w += v0.w;
        }
        {
            float dx = v1.x - c1.x, dy = v1.y - c1.y, dz = v1.z - c1.z, dw = v1.w - c1.w;
            d += dx * dx + dy * dy + dz * dz + dw * dw;
            a1.x += v1.x; a1.y += v1.y; a1.z += v1.z; a1.w += v1.w;
        }
        {
            float dx = v2.x - c2.x, dy = v2.y - c2.y, dz = v2.z - c2.z, dw = v2.w - c2.w;
            d += dx * dx + dy * dy + dz * dz + dw * dw;
            a2.x += v2.x; a2.y += v2.y; a2.z += v2.z; a2.w += v2.w;
        }
        if (tail) {
            float dx = v3.x - c3.x, dy = v3.y - c3.y, dz = v3.z - c3.z, dw = v3.w - c3.w;
            d += dx * dx + dy * dy + dz * dz + dw * dw;
            a3.x += v3.x; a3.y += v3.y; a3.z += v3.z; a3.w += v3.w;
        }
        const float se = wave_sum(e);
        const float sd = wave_sum(d);

        // x[b][c]: block-uniform source slot, single shuffle broadcast
        float4 xj = (j_src == 0) ? v0 : (j_src == 1) ? v1 : (j_src == 2) ? v2 : v3;
        float cand = (comp == 0) ? xj.x : (comp == 1) ? xj.y : (comp == 2) ? xj.z : xj.w;
        const float xy = __shfl(cand, lane_src, 64);

        ce_acc += -(xy - rmax - __logf(se));
        s2_acc += sd;

        v0 = n0; v1 = n1; v2 = n2; v3 = n3;
    }

    // deterministic staged merge of per-wave partial sums into smx
    for (int w = 0; w < 4; w++) {
        if (wid == w) {
            if (w == 0) {
                smx[lane] = a0; smx[lane + 64] = a1; smx[lane + 128] = a2;
                if (tail) smx[lane + 192] = a3;
            } else {
                float4 s;
                s = smx[lane];      s.x += a0.x; s.y += a0.y; s.z += a0.z; s.w += a0.w; smx[lane] = s;
                s = smx[lane + 64]; s.x += a1.x; s.y += a1.y; s.z += a1.z; s.w += a1.w; smx[lane + 64] = s;
                s = smx[lane + 128]; s.x += a2.x; s.y += a2.y; s.z += a2.z; s.w += a2.w; smx[lane + 128] = s;
                if (tail) { s = smx[lane + 192]; s.x += a3.x; s.y += a3.y; s.z += a3.z; s.w += a3.w; smx[lane + 192] = s; }
            }
        }
        __syncthreads();
    }
    if (lane == 0) { sb[wid] = ce_acc; sb[4 + wid] = s2_acc; }
    __syncthreads();

    // epilogue on wave 0 only
    if (wid == 0) {
        const float inv = (n > 0) ? 1.f / (float)n : 0.f;
        const float has = (n > 0) ? 1.f : 0.f;
        float lsq = 0.f, lmd2 = 0.f;
        float4* ncrow = (float4*)(new_centers + (size_t)c * NF);
#pragma unroll
        for (int j = 0; j < 4; j++) {
            const int idx = lane + 64 * j;
            if (idx < NV) {
                const float4 s = smx[idx];
                const float4 cv = (j == 0) ? c0 : (j == 1) ? c1 : (j == 2) ? c2 : c3;
                float4 md, nc;
                md.x = has * (s.x * inv - cv.x);
                md.y = has * (s.y * inv - cv.y);
                md.z = has * (s.z * inv - cv.z);
                md.w = has * (s.w * inv - cv.w);
                nc.x = cv.x + ALPHA_C * md.x; nc.y = cv.y + ALPHA_C * md.y;
                nc.z = cv.z + ALPHA_C * md.z; nc.w = cv.w + ALPHA_C * md.w;
                ncrow[idx] = nc;
                lsq  += nc.x * nc.x + nc.y * nc.y + nc.z * nc.z + nc.w * nc.w;
                lmd2 += md.x * md.x + md.y * md.y + md.z * md.z + md.w * md.w;
            }
        }
        const float sq = wave_sum(lsq);
        const float md2 = wave_sum(lmd2);
        if (lane == 0) {
            const float ces = sb[0] + sb[1] + sb[2] + sb[3];
            const float s2 = sb[4] + sb[5] + sb[6] + sb[7];
            // per-class intra mean: S2/n - alpha*(2-alpha)*||md||^2
            const float intra = (n > 0) ? (s2 * inv - ALPHA_C * (2.f - ALPHA_C) * md2) : 0.f;
            partials[c] = make_float4(ces, s2, sq, intra);
        }
    }
}

// Partial column sums, no atomics: block (bx,by) writes s_part[by*NF + f].
__global__ __launch_bounds__(256) void col_partial(
    const float* __restrict__ new_centers, float* __restrict__ s_part) {
    const int f = blockIdx.x * 256 + threadIdx.x;
    if (f >= NF) return;
    float acc = 0.f;
    for (int c = blockIdx.y; c < NC; c += gridDim.y)
        acc += new_centers[(size_t)c * NF + f];
    s_part[blockIdx.y * NF + f] = acc;
}

__global__ __launch_bounds__(1024) void finalize(
    const float* __restrict__ s_part, const float4* __restrict__ partials,
    float* __restrict__ out) {
    __shared__ float sb[80];
    const int t = threadIdx.x;
    float ssq = 0.f, ces = 0.f, s2 = 0.f, sq = 0.f, intra = 0.f;
    if (t < NC) {
        float s = 0.f;
#pragma unroll
        for (int k = 0; k < 16; k++) s += s_part[k * NF + t];
        ssq = s * s;
        float4 p = partials[t];
        ces = p.x; s2 = p.y; sq = p.z; intra = p.w;
    }
    float w0 = wave_sum(ssq), w1 = wave_sum(ces), w2 = wave_sum(s2);
    float w3 = wave_sum(sq), w4 = wave_sum(intra);
    const int wid = t >> 6, lane = t & 63;
    if (lane == 0) {
        sb[wid] = w0; sb[16 + wid] = w1; sb[32 + wid] = w2;
        sb[48 + wid] = w3; sb[64 + wid] = w4;
    }
    __syncthreads();
    if (t == 0) {
        float Sssq = 0.f, Sces = 0.f, Ss2 = 0.f, Ssq = 0.f, Sintra = 0.f;
        for (int k = 0; k < 16; k++) {
            Sssq += sb[k]; Sces += sb[16 + k]; Ss2 += sb[32 + k];
            Ssq += sb[48 + k]; Sintra += sb[64 + k];
        }
        float cem = Sces / (float)NB;
        float cl = Ss2 / (float)NB;
        float num_pairs = (float)NC * (float)(NC - 1) * 0.5f;
        float inter = ((float)NC * Ssq - Sssq) / num_pairs;
        float intra_l = Sintra / (float)NC;
        out[0] = cem + BETA_C * cl + GAMMA_C * inter + GAMMA_C * intra_l;
    }
}

extern "C" void kernel_launch(void* const* d_in, const int* in_sizes, int n_in,
                              void* d_out, int out_size, void* d_ws, size_t ws_size,
                              hipStream_t stream) {
    const float* x = (const float*)d_in[0];
    const int* y = (const int*)d_in[1];
    const float* centers = (const float*)d_in[2];
    float* out = (float*)d_out;

    char* ws = (char*)d_ws;
    float* s_part      = (float*)(ws);                 // 16*1000*4 = 64,000 B
    float4* partials   = (float4*)(ws + 64000);        // 16,000 B
    float* new_centers = (float*)(ws + 80000);         // 4,000,000 B
    // everything read is written this launch -- no memset needed

    class_fused<<<NC, 256, 0, stream>>>(x, y, centers, new_centers, partials);
    dim3 cgrid(4, 16);
    col_partial<<<cgrid, 256, 0, stream>>>(new_centers, s_part);
    finalize<<<1, 1024, 0, stream>>>(s_part, partials, out);
}